// Round 2
// baseline (607.115 us; speedup 1.0000x reference)
//
#include <hip/hip_runtime.h>
#include <hip/hip_bf16.h>

#define N_NODES 50000
#define N_EDGES 1600000
#define IN_DIM 1024
#define HID 128
#define AGG_BLOCKS 1536         // fully resident: 256 CU x 6 blocks/CU; %8 -> XCD
#define SL_WAVES 1536           // waves per feature-slice (AGG_BLOCKS/8 * 2 * 4)

typedef __bf16 bf16x8 __attribute__((ext_vector_type(8)));
typedef float f32x4 __attribute__((ext_vector_type(4)));
typedef __bf16 bf16x4 __attribute__((ext_vector_type(4)));

// bf16-pair (packed in uint) -> 2 floats (features 2l = low, 2l+1 = high)
__device__ __forceinline__ float2 bf2f(unsigned u) {
    return make_float2(__uint_as_float(u << 16), __uint_as_float(u & 0xffff0000u));
}
__device__ __forceinline__ float lrelu(float v) { return v > 0.f ? v : 0.2f * v; }

// ---------------------------------------------------------------- prep: zero deg/out + W^T->bf16
__global__ void prep_kernel(const float* __restrict__ W, __bf16* __restrict__ wt,
                            int* __restrict__ deg, float* __restrict__ out, int out_n) {
    int i = blockIdx.x * 256 + threadIdx.x;       // grid covers 131072
    if (i < N_NODES) deg[i] = 0;
    if (i < out_n) out[i] = 0.0f;
    if (i < HID * IN_DIM) {
        int n = i >> 10, k = i & 1023;
        wt[i] = (__bf16)W[(size_t)k * HID + n];
    }
}

// ---------------------------------------------------------------- GEMM h = x @ W (bf16 MFMA)
// BM=64 x BN=128 (full HID), BK=32, 782 blocks. Double-buffered LDS, one barrier
// per k-iter, register prefetch of next tile. Epilogue writes h2 in SLICED
// layout: h2s[slice][node][32 features] (64B per node-slice = one cache line) so
// the aggregate pass can keep one slice resident in each XCD's L2.
__global__ __launch_bounds__(256) void gemm_kernel(const float* __restrict__ x,
                                                   const __bf16* __restrict__ wt,
                                                   __bf16* __restrict__ h2s,
                                                   const float* __restrict__ att_s,
                                                   const float* __restrict__ att_d,
                                                   float* __restrict__ o_as,
                                                   float* __restrict__ o_ad,
                                                   float* __restrict__ o_ps) {
    __shared__ __bf16 xa[2][64][40];
    __shared__ __bf16 wb[2][128][40];
    const int t = threadIdx.x;
    const int m0 = blockIdx.x * 64;
    const int wid = t >> 6, lane = t & 63;
    const int lm = lane & 15, q8 = (lane >> 4) * 8;
    const int rw0 = wid * 16;

    float4 xs_reg[2];
    uint2  ws_reg[4];

    auto stage_regs = [&](int k0) {
#pragma unroll
        for (int l = 0; l < 2; ++l) {
            int f = t + l * 256;
            int row = f >> 3, kq = f & 7;
            int gr = m0 + row;
            float4 v = make_float4(0.f, 0.f, 0.f, 0.f);
            if (gr < N_NODES)
                v = *(const float4*)(x + (size_t)gr * IN_DIM + k0 + kq * 4);
            xs_reg[l] = v;
        }
#pragma unroll
        for (int l = 0; l < 4; ++l) {
            int f = t + l * 256;
            int n = f >> 3, c = f & 7;
            ws_reg[l] = *(const uint2*)(wt + (size_t)n * IN_DIM + k0 + c * 4);
        }
    };
    auto regs_to_lds = [&](int b) {
#pragma unroll
        for (int l = 0; l < 2; ++l) {
            int f = t + l * 256;
            int row = f >> 3, kq = f & 7;
            bf16x4 v;
            v[0] = (__bf16)xs_reg[l].x; v[1] = (__bf16)xs_reg[l].y;
            v[2] = (__bf16)xs_reg[l].z; v[3] = (__bf16)xs_reg[l].w;
            *(bf16x4*)&xa[b][row][kq * 4] = v;
        }
#pragma unroll
        for (int l = 0; l < 4; ++l) {
            int f = t + l * 256;
            int n = f >> 3, c = f & 7;
            *(uint2*)&wb[b][n][c * 4] = ws_reg[l];
        }
    };

    f32x4 acc[8] = {};
    stage_regs(0);
    regs_to_lds(0);
    __syncthreads();
    for (int it = 0; it < 32; ++it) {
        const int cur = it & 1;
        if (it + 1 < 32) stage_regs((it + 1) * 32);   // global loads in flight during MFMA
        bf16x8 af = *(const bf16x8*)&xa[cur][rw0 + lm][q8];
#pragma unroll
        for (int ct = 0; ct < 8; ++ct) {
            bf16x8 bfr = *(const bf16x8*)&wb[cur][ct * 16 + lm][q8];
            acc[ct] = __builtin_amdgcn_mfma_f32_16x16x32_bf16(af, bfr, acc[ct], 0, 0, 0);
        }
        if (it + 1 < 32) {
            regs_to_lds(cur ^ 1);     // write OTHER buffer: no read-write conflict
            __syncthreads();          // make writes visible for next iter's reads
        }
    }
    // epilogue: C/D layout col=lane&15, row=(lane>>4)*4+reg ; fused att dots
    const int quad = lane >> 4;
    float attsf[8], attdf[8];
#pragma unroll
    for (int ct = 0; ct < 8; ++ct) {
        attsf[ct] = att_s[ct * 16 + lm];
        attdf[ct] = att_d[ct * 16 + lm];
    }
#pragma unroll
    for (int reg = 0; reg < 4; ++reg) {
        int row = m0 + rw0 + quad * 4 + reg;
        float ps = 0.f, pd = 0.f;
#pragma unroll
        for (int ct = 0; ct < 8; ++ct) {
            float v = acc[ct][reg];
            ps = fmaf(v, attsf[ct], ps);
            pd = fmaf(v, attdf[ct], pd);
        }
#pragma unroll
        for (int o = 8; o; o >>= 1) {
            ps += __shfl_xor(ps, o);
            pd += __shfl_xor(pd, o);
        }
        if (row < N_NODES) {
            if (lm == 0) {
                o_as[row] = ps; o_ad[row] = pd;
                o_ps[row] = __expf(lrelu(ps + pd));   // self-loop weight, precomputed
            }
            // sliced write: feature f = ct*16+lm -> slice ct>>1, within (ct&1)*16+lm
#pragma unroll
            for (int ct = 0; ct < 8; ++ct)
                h2s[((size_t)(ct >> 1) * N_NODES + row) * 32 + (ct & 1) * 16 + lm] =
                    (__bf16)acc[ct][reg];
        }
    }
}

// ---------------------------------------------------------------- CSR build
__global__ void hist_kernel(const int* __restrict__ ei, int* __restrict__ deg) {
    int e = blockIdx.x * 256 + threadIdx.x;
    if (e < N_EDGES) atomicAdd(&deg[ei[N_EDGES + e]], 1);
}

__global__ void scan1_kernel(const int* __restrict__ deg, int* __restrict__ bsum) {
    int b = blockIdx.x, t = threadIdx.x;
    int base = b * 1024 + t * 4;
    int s = 0;
#pragma unroll
    for (int j = 0; j < 4; ++j) {
        int idx = base + j;
        if (idx < N_NODES) s += deg[idx];
    }
    for (int o = 32; o; o >>= 1) s += __shfl_xor(s, o);
    __shared__ int wsum[4];
    int lane = t & 63, w = t >> 6;
    if (lane == 0) wsum[w] = s;
    __syncthreads();
    if (t == 0) bsum[b] = wsum[0] + wsum[1] + wsum[2] + wsum[3];
}

__global__ void scan2_kernel(const int* __restrict__ bsum, int* __restrict__ boff,
                             int* __restrict__ rowstart, int nb) {
    if (threadIdx.x == 0 && blockIdx.x == 0) {
        int run = 0;
        for (int i = 0; i < nb; ++i) { boff[i] = run; run += bsum[i]; }
        rowstart[N_NODES] = run;
    }
}

// also materializes cursor = rowstart copy for scatter's atomic slot claim
__global__ void scan3_kernel(const int* __restrict__ deg, const int* __restrict__ boff,
                             int* __restrict__ rowstart, int* __restrict__ cursor) {
    int b = blockIdx.x, t = threadIdx.x;
    int base = b * 1024 + t * 4;
    int v[4]; int s = 0;
#pragma unroll
    for (int j = 0; j < 4; ++j) {
        int idx = base + j;
        v[j] = (idx < N_NODES) ? deg[idx] : 0;
        s += v[j];
    }
    int lane = t & 63, w = t >> 6;
    int inc = s;
    for (int o = 1; o < 64; o <<= 1) {
        int u = __shfl_up(inc, o);
        if (lane >= o) inc += u;
    }
    __shared__ int wt[4];
    if (lane == 63) wt[w] = inc;
    __syncthreads();
    int woff = 0;
    for (int i = 0; i < w; ++i) woff += wt[i];
    int run = woff + inc - s + boff[b];
#pragma unroll
    for (int j = 0; j < 4; ++j) {
        int idx = base + j;
        if (idx < N_NODES) {
            rowstart[idx] = run;
            cursor[idx] = run;
            run += v[j];
        }
    }
}

// scatter: slot via atomic cursor (order within a row is irrelevant — commutative
// sum). Payload is (src, p_e) with p_e = exp(lrelu(a_src[s]+a_dst[d])) FULLY
// precomputed here, so the hot aggregate loop does zero transcendental work.
__global__ void scatter_kernel(const int* __restrict__ ei, int* __restrict__ cursor,
                               uint2* __restrict__ csrp, const float* __restrict__ a_src,
                               const float* __restrict__ a_dst) {
    int e = blockIdx.x * 256 + threadIdx.x;
    if (e >= N_EDGES) return;
    int s = ei[e], d = ei[N_EDGES + e];
    int slot = atomicAdd(&cursor[d], 1);
    float pe = __expf(lrelu(a_src[s] + a_dst[d]));
    uint2 v; v.x = (unsigned)s; v.y = __float_as_uint(pe);
    csrp[slot] = v;
}

// ---------------------------------------------------------------- aggregate+pool
// XCD-LOCAL FEATURE SLICING: features split into 4 slices of 32 (64B/node = one
// cache line). blockIdx%8 -> XCD (grid fully resident at 6 blocks/CU), slice =
// xcd>>1, so each XCD only gathers from ONE 3.2MB slice -> fits its 4MB L2.
// Random row gathers become local-L2 hits instead of cross-fabric L3 traffic.
// Quad q of the wave owns edge 4g+q; (src,pe) comes from a 16-lane-same-address
// csrp load (1 L2-hot transaction, no DS ops). Lane ql gathers dword ql of the
// row-slice = features {2ql, 2ql+1}. Cross-quad shfl_xor(16/32) folds the 4
// edge partitions and the softmax denominator.
__global__ __launch_bounds__(256, 6) void aggregate_kernel(
    const unsigned* __restrict__ h2s, const float* __restrict__ pself_a,
    const int* __restrict__ rowstart, const uint2* __restrict__ csrp,
    const float* __restrict__ bias, const int* __restrict__ batch,
    float* __restrict__ out) {
    const int wid = threadIdx.x >> 6, lane = threadIdx.x & 63;
    const int quad = lane >> 4, ql = lane & 15;
    const int bid = blockIdx.x;
    const int xcd = bid & 7;
    const int slice = xcd >> 1;                       // 2 XCDs per slice
    const int sub = ((bid >> 3) << 1) | (xcd & 1);    // 0..383 within slice
    const int w = sub * 4 + wid;                      // 0..1535 within slice
    const unsigned* __restrict__ hs = h2s + (size_t)slice * N_NODES * 16;
    const int q = N_NODES / SL_WAVES;
    const int r = N_NODES - q * SL_WAVES;
    int n0 = w * q + (w < r ? w : r);
    int n1 = n0 + q + (w < r ? 1 : 0);
    const float2 bv = ((const float2*)bias)[slice * 16 + ql];

    int gcur = -1;
    float m0 = 0.f, m1 = 0.f;
    for (int n = n0; n < n1; ++n) {
        int rs = rowstart[n], re = rowstart[n + 1];
        float psf = pself_a[n];
        float a0 = 0.f, a1 = 0.f, pws = 0.f;
        for (int e0 = rs; e0 < re; e0 += 32) {        // 8 groups x 4 edges per pass
            unsigned uu[8]; float pw[8];
#pragma unroll
            for (int i = 0; i < 8; ++i) {
                int idx = e0 + (i << 2) + quad;
                uint2 e = make_uint2(0u, 0u);         // pe=0 for padded groups
                if (idx < re) e = csrp[idx];
                pw[i] = __uint_as_float(e.y);
                uu[i] = hs[(size_t)e.x * 16 + ql];    // row-0 L1-hit when padded
            }
#pragma unroll
            for (int i = 0; i < 8; ++i) {
                float2 f = bf2f(uu[i]);
                a0 = fmaf(pw[i], f.x, a0);
                a1 = fmaf(pw[i], f.y, a1);
                pws += pw[i];
            }
        }
        // fold the 4 quad partitions (edges) + denominator
        a0 += __shfl_xor(a0, 16); a0 += __shfl_xor(a0, 32);
        a1 += __shfl_xor(a1, 16); a1 += __shfl_xor(a1, 32);
        pws += __shfl_xor(pws, 16); pws += __shfl_xor(pws, 32);
        // self-loop contribution (added once, post-reduce, by every lane)
        float2 hv = bf2f(hs[(size_t)n * 16 + ql]);
        a0 = fmaf(psf, hv.x, a0);
        a1 = fmaf(psf, hv.y, a1);
        float inv = 1.0f / (psf + pws);
        float o0 = fmaxf(fmaf(a0, inv, bv.x), 0.f);
        float o1 = fmaxf(fmaf(a1, inv, bv.y), 0.f);
        int g = batch[n];
        if (g != gcur) {
            if (gcur >= 0 && quad == 0) {
                unsigned* outp = (unsigned*)(out + (size_t)gcur * HID + slice * 32);
                atomicMax(&outp[2 * ql],     __float_as_uint(m0));
                atomicMax(&outp[2 * ql + 1], __float_as_uint(m1));
            }
            gcur = g; m0 = o0; m1 = o1;
        } else {
            m0 = fmaxf(m0, o0); m1 = fmaxf(m1, o1);
        }
    }
    if (gcur >= 0 && quad == 0) {
        unsigned* outp = (unsigned*)(out + (size_t)gcur * HID + slice * 32);
        atomicMax(&outp[2 * ql],     __float_as_uint(m0));
        atomicMax(&outp[2 * ql + 1], __float_as_uint(m1));
    }
}

// ---------------------------------------------------------------- launch
extern "C" void kernel_launch(void* const* d_in, const int* in_sizes, int n_in,
                              void* d_out, int out_size, void* d_ws, size_t ws_size,
                              hipStream_t stream) {
    const float* x     = (const float*)d_in[0];
    const float* W     = (const float*)d_in[1];
    const float* att_s = (const float*)d_in[2];
    const float* att_d = (const float*)d_in[3];
    const float* bias  = (const float*)d_in[4];
    const int*   ei    = (const int*)d_in[5];
    const int*   batch = (const int*)d_in[6];
    float*       out   = (float*)d_out;

    char* ws = (char*)d_ws;
    size_t off = 0;
    auto alloc = [&](size_t bytes) -> void* {
        void* p = ws + off;
        off += (bytes + 255) & ~(size_t)255;
        return p;
    };
    const int NB = (N_NODES + 1023) / 1024;   // 49
    __bf16* h2       = (__bf16*)alloc((size_t)N_NODES * HID * 2);
    __bf16* wt       = (__bf16*)alloc((size_t)HID * IN_DIM * 2);
    float*  a_src    = (float*)alloc((size_t)N_NODES * 4);
    float*  a_dst    = (float*)alloc((size_t)N_NODES * 4);
    float*  pself    = (float*)alloc((size_t)N_NODES * 4);
    int*    deg      = (int*)alloc((size_t)N_NODES * 4);
    int*    rowstart = (int*)alloc((size_t)(N_NODES + 1) * 4);
    int*    cursor   = (int*)alloc((size_t)N_NODES * 4);
    int*    bsum     = (int*)alloc((size_t)NB * 4);
    int*    boff     = (int*)alloc((size_t)NB * 4);
    uint2*  csrp     = (uint2*)alloc((size_t)N_EDGES * 8);
    (void)ws_size; (void)in_sizes; (void)n_in;

    hipLaunchKernelGGL(prep_kernel, dim3(512), dim3(256), 0, stream,
                       W, wt, deg, out, out_size);
    hipLaunchKernelGGL(gemm_kernel, dim3((N_NODES + 63) / 64), dim3(256), 0, stream,
                       x, wt, h2, att_s, att_d, a_src, a_dst, pself);
    hipLaunchKernelGGL(hist_kernel, dim3((N_EDGES + 255) / 256), dim3(256), 0, stream,
                       ei, deg);
    hipLaunchKernelGGL(scan1_kernel, dim3(NB), dim3(256), 0, stream, deg, bsum);
    hipLaunchKernelGGL(scan2_kernel, dim3(1), dim3(64), 0, stream, bsum, boff, rowstart, NB);
    hipLaunchKernelGGL(scan3_kernel, dim3(NB), dim3(256), 0, stream, deg, boff, rowstart, cursor);
    hipLaunchKernelGGL(scatter_kernel, dim3((N_EDGES + 255) / 256), dim3(256), 0, stream,
                       ei, cursor, csrp, a_src, a_dst);
    hipLaunchKernelGGL(aggregate_kernel, dim3(AGG_BLOCKS), dim3(256), 0, stream,
                       (const unsigned*)h2, pself, rowstart, csrp, bias, batch, out);
}

// Round 3
// 583.162 us; speedup vs baseline: 1.0411x; 1.0411x over previous
//
#include <hip/hip_runtime.h>
#include <hip/hip_bf16.h>

#define N_NODES 50000
#define N_EDGES 1600000
#define IN_DIM 1024
#define HID 128
#define AGG_WAVES 8192          // 2048 blocks x 4 waves = 32 waves/CU at launch_bounds(256,8)

typedef __bf16 bf16x8 __attribute__((ext_vector_type(8)));
typedef float f32x4 __attribute__((ext_vector_type(4)));
typedef __bf16 bf16x4 __attribute__((ext_vector_type(4)));

// bf16-pair (packed in uint) -> 2 floats (features 2l = low, 2l+1 = high)
__device__ __forceinline__ float2 bf2f(unsigned u) {
    return make_float2(__uint_as_float(u << 16), __uint_as_float(u & 0xffff0000u));
}
__device__ __forceinline__ float lrelu(float v) { return v > 0.f ? v : 0.2f * v; }
// fp16 bits (in low 16 of arg) -> float
__device__ __forceinline__ float f16tof(unsigned bits) {
    return (float)__builtin_bit_cast(_Float16, (unsigned short)bits);
}

// ---------------------------------------------------------------- prep: zero deg/out + W^T->bf16
__global__ void prep_kernel(const float* __restrict__ W, __bf16* __restrict__ wt,
                            int* __restrict__ deg, float* __restrict__ out, int out_n) {
    int i = blockIdx.x * 256 + threadIdx.x;       // grid covers 131072
    if (i < N_NODES) deg[i] = 0;
    if (i < out_n) out[i] = 0.0f;
    if (i < HID * IN_DIM) {
        int n = i >> 10, k = i & 1023;
        wt[i] = (__bf16)W[(size_t)k * HID + n];
    }
}

// ---------------------------------------------------------------- GEMM h = x @ W (bf16 MFMA)
// BM=64 x BN=128 (full HID), BK=32, 782 blocks. Double-buffered LDS, one barrier
// per k-iter, register prefetch of next tile. Flat h2 layout (R2's sliced layout
// reverted). Epilogue emits a_src/a_dst and pself = exp(lrelu(a_src+a_dst)).
__global__ __launch_bounds__(256) void gemm_kernel(const float* __restrict__ x,
                                                   const __bf16* __restrict__ wt,
                                                   __bf16* __restrict__ h2,
                                                   const float* __restrict__ att_s,
                                                   const float* __restrict__ att_d,
                                                   float* __restrict__ o_as,
                                                   float* __restrict__ o_ad,
                                                   float* __restrict__ o_ps) {
    __shared__ __bf16 xa[2][64][40];
    __shared__ __bf16 wb[2][128][40];
    const int t = threadIdx.x;
    const int m0 = blockIdx.x * 64;
    const int wid = t >> 6, lane = t & 63;
    const int lm = lane & 15, q8 = (lane >> 4) * 8;
    const int rw0 = wid * 16;

    float4 xs_reg[2];
    uint2  ws_reg[4];

    auto stage_regs = [&](int k0) {
#pragma unroll
        for (int l = 0; l < 2; ++l) {
            int f = t + l * 256;
            int row = f >> 3, kq = f & 7;
            int gr = m0 + row;
            float4 v = make_float4(0.f, 0.f, 0.f, 0.f);
            if (gr < N_NODES)
                v = *(const float4*)(x + (size_t)gr * IN_DIM + k0 + kq * 4);
            xs_reg[l] = v;
        }
#pragma unroll
        for (int l = 0; l < 4; ++l) {
            int f = t + l * 256;
            int n = f >> 3, c = f & 7;
            ws_reg[l] = *(const uint2*)(wt + (size_t)n * IN_DIM + k0 + c * 4);
        }
    };
    auto regs_to_lds = [&](int b) {
#pragma unroll
        for (int l = 0; l < 2; ++l) {
            int f = t + l * 256;
            int row = f >> 3, kq = f & 7;
            bf16x4 v;
            v[0] = (__bf16)xs_reg[l].x; v[1] = (__bf16)xs_reg[l].y;
            v[2] = (__bf16)xs_reg[l].z; v[3] = (__bf16)xs_reg[l].w;
            *(bf16x4*)&xa[b][row][kq * 4] = v;
        }
#pragma unroll
        for (int l = 0; l < 4; ++l) {
            int f = t + l * 256;
            int n = f >> 3, c = f & 7;
            *(uint2*)&wb[b][n][c * 4] = ws_reg[l];
        }
    };

    f32x4 acc[8] = {};
    stage_regs(0);
    regs_to_lds(0);
    __syncthreads();
    for (int it = 0; it < 32; ++it) {
        const int cur = it & 1;
        if (it + 1 < 32) stage_regs((it + 1) * 32);   // global loads in flight during MFMA
        bf16x8 af = *(const bf16x8*)&xa[cur][rw0 + lm][q8];
#pragma unroll
        for (int ct = 0; ct < 8; ++ct) {
            bf16x8 bfr = *(const bf16x8*)&wb[cur][ct * 16 + lm][q8];
            acc[ct] = __builtin_amdgcn_mfma_f32_16x16x32_bf16(af, bfr, acc[ct], 0, 0, 0);
        }
        if (it + 1 < 32) {
            regs_to_lds(cur ^ 1);     // write OTHER buffer: no read-write conflict
            __syncthreads();          // make writes visible for next iter's reads
        }
    }
    // epilogue: C/D layout col=lane&15, row=(lane>>4)*4+reg ; fused att dots
    const int quad = lane >> 4;
    float attsf[8], attdf[8];
#pragma unroll
    for (int ct = 0; ct < 8; ++ct) {
        attsf[ct] = att_s[ct * 16 + lm];
        attdf[ct] = att_d[ct * 16 + lm];
    }
#pragma unroll
    for (int reg = 0; reg < 4; ++reg) {
        int row = m0 + rw0 + quad * 4 + reg;
        float ps = 0.f, pd = 0.f;
#pragma unroll
        for (int ct = 0; ct < 8; ++ct) {
            float v = acc[ct][reg];
            ps = fmaf(v, attsf[ct], ps);
            pd = fmaf(v, attdf[ct], pd);
        }
#pragma unroll
        for (int o = 8; o; o >>= 1) {
            ps += __shfl_xor(ps, o);
            pd += __shfl_xor(pd, o);
        }
        if (row < N_NODES) {
            if (lm == 0) {
                o_as[row] = ps; o_ad[row] = pd;
                o_ps[row] = __expf(lrelu(ps + pd));   // self-loop weight, precomputed
            }
#pragma unroll
            for (int ct = 0; ct < 8; ++ct)
                h2[(size_t)row * HID + ct * 16 + lm] = (__bf16)acc[ct][reg];
        }
    }
}

// ---------------------------------------------------------------- CSR build
__global__ void hist_kernel(const int* __restrict__ ei, int* __restrict__ deg) {
    int e = blockIdx.x * 256 + threadIdx.x;
    if (e < N_EDGES) atomicAdd(&deg[ei[N_EDGES + e]], 1);
}

__global__ void scan1_kernel(const int* __restrict__ deg, int* __restrict__ bsum) {
    int b = blockIdx.x, t = threadIdx.x;
    int base = b * 1024 + t * 4;
    int s = 0;
#pragma unroll
    for (int j = 0; j < 4; ++j) {
        int idx = base + j;
        if (idx < N_NODES) s += deg[idx];
    }
    for (int o = 32; o; o >>= 1) s += __shfl_xor(s, o);
    __shared__ int wsum[4];
    int lane = t & 63, w = t >> 6;
    if (lane == 0) wsum[w] = s;
    __syncthreads();
    if (t == 0) bsum[b] = wsum[0] + wsum[1] + wsum[2] + wsum[3];
}

__global__ void scan2_kernel(const int* __restrict__ bsum, int* __restrict__ boff,
                             int* __restrict__ rowstart, int nb) {
    if (threadIdx.x == 0 && blockIdx.x == 0) {
        int run = 0;
        for (int i = 0; i < nb; ++i) { boff[i] = run; run += bsum[i]; }
        rowstart[N_NODES] = run;
    }
}

// also materializes cursor = rowstart copy for scatter's atomic slot claim
__global__ void scan3_kernel(const int* __restrict__ deg, const int* __restrict__ boff,
                             int* __restrict__ rowstart, int* __restrict__ cursor) {
    int b = blockIdx.x, t = threadIdx.x;
    int base = b * 1024 + t * 4;
    int v[4]; int s = 0;
#pragma unroll
    for (int j = 0; j < 4; ++j) {
        int idx = base + j;
        v[j] = (idx < N_NODES) ? deg[idx] : 0;
        s += v[j];
    }
    int lane = t & 63, w = t >> 6;
    int inc = s;
    for (int o = 1; o < 64; o <<= 1) {
        int u = __shfl_up(inc, o);
        if (lane >= o) inc += u;
    }
    __shared__ int wt[4];
    if (lane == 63) wt[w] = inc;
    __syncthreads();
    int woff = 0;
    for (int i = 0; i < w; ++i) woff += wt[i];
    int run = woff + inc - s + boff[b];
#pragma unroll
    for (int j = 0; j < 4; ++j) {
        int idx = base + j;
        if (idx < N_NODES) {
            rowstart[idx] = run;
            cursor[idx] = run;
            run += v[j];
        }
    }
}

// scatter: slot via atomic cursor. PACKED payload: u16 src | fp16 pe (4B/edge,
// half the csrp traffic of uint2 and ONE bpermute instead of two in aggregate).
// src < 65536 OK (N=50000); pe = exp(lrelu(.)) lands in [~e^-1, ~e^3] -- far
// inside fp16 range; 2^-11 rel error is ~10x below the bf16 noise floor.
__global__ void scatter_kernel(const int* __restrict__ ei, int* __restrict__ cursor,
                               unsigned* __restrict__ csrp, const float* __restrict__ a_src,
                               const float* __restrict__ a_dst) {
    int e = blockIdx.x * 256 + threadIdx.x;
    if (e >= N_EDGES) return;
    int s = ei[e], d = ei[N_EDGES + e];
    int slot = atomicAdd(&cursor[d], 1);
    float pe = __expf(lrelu(a_src[s] + a_dst[d]));
    unsigned short hb = __builtin_bit_cast(unsigned short, (_Float16)pe);
    csrp[slot] = (unsigned)s | ((unsigned)hb << 16);
}

// ---------------------------------------------------------------- aggregate+pool
// R0's best-measured shape restored: lane owns features {2l,2l+1}; 64-edge chunk
// staged per lane; 16-deep register batch of shfl-broadcast packed (src|pe) ->
// 16 independent full-row gathers in flight. Diagnosis from R2 counters: kernel
// is LATENCY-bound (HBM 5%, VALU 45%, no conflicts) -> levers here are MLP:
// 32 waves/CU (launch_bounds(256,8), was 6), 1 bpermute/edge (packed payload),
// and 32-bit gather offsets (SGPR base + voffset, no 64-bit carries).
__global__ __launch_bounds__(256, 8) void aggregate_kernel(
    const unsigned* __restrict__ h2u, const float* __restrict__ pself_a,
    const int* __restrict__ rowstart, const unsigned* __restrict__ csrp,
    const float* __restrict__ bias, const int* __restrict__ batch,
    float* __restrict__ out) {
    const int wid = threadIdx.x >> 6, lane = threadIdx.x & 63;
    const int w = blockIdx.x * 4 + wid;
    const int q = N_NODES / AGG_WAVES;
    const int r = N_NODES - q * AGG_WAVES;
    int n0 = w * q + (w < r ? w : r);
    int n1 = n0 + q + (w < r ? 1 : 0);
    const float b0 = bias[2 * lane], b1 = bias[2 * lane + 1];

    int gcur = -1;
    float m0 = 0.f, m1 = 0.f;
    for (int n = n0; n < n1; ++n) {
        int rs = rowstart[n], re = rowstart[n + 1];
        float psf = pself_a[n];
        float2 hv = bf2f(h2u[((unsigned)n << 6) | (unsigned)lane]);
        float denom = psf;
        float2 acc = make_float2(psf * hv.x, psf * hv.y);
        for (int base = rs; base < re; base += 64) {
            int cnt = re - base; if (cnt > 64) cnt = 64;
            unsigned sp = 0u;                 // src=0, pe=0 for invalid lanes
            if (base + lane < re) sp = csrp[base + lane];
            float ds = f16tof(sp >> 16);      // own edge weight
            for (int o = 32; o; o >>= 1) ds += __shfl_xor(ds, o);
            denom += ds;
            for (int e = 0; e < cnt; e += 16) {
                unsigned bb[16], uu[16];
#pragma unroll
                for (int i = 0; i < 16; ++i) {
                    bb[i] = (unsigned)__shfl((int)sp, e + i);
                    uu[i] = h2u[((bb[i] & 0xffffu) << 6) | (unsigned)lane];
                }
#pragma unroll
                for (int i = 0; i < 16; ++i) {
                    float2 g = bf2f(uu[i]);
                    float p = f16tof(bb[i] >> 16);
                    acc.x = fmaf(p, g.x, acc.x);
                    acc.y = fmaf(p, g.y, acc.y);
                }
            }
        }
        float inv = 1.0f / denom;
        float o0 = fmaxf(fmaf(acc.x, inv, b0), 0.0f);
        float o1 = fmaxf(fmaf(acc.y, inv, b1), 0.0f);
        int g = batch[n];
        if (g != gcur) {
            if (gcur >= 0) {
                unsigned* outp = (unsigned*)(out + (size_t)gcur * HID);
                atomicMax(&outp[2 * lane], __float_as_uint(m0));
                atomicMax(&outp[2 * lane + 1], __float_as_uint(m1));
            }
            gcur = g; m0 = o0; m1 = o1;
        } else {
            m0 = fmaxf(m0, o0); m1 = fmaxf(m1, o1);
        }
    }
    if (gcur >= 0) {
        unsigned* outp = (unsigned*)(out + (size_t)gcur * HID);
        atomicMax(&outp[2 * lane], __float_as_uint(m0));
        atomicMax(&outp[2 * lane + 1], __float_as_uint(m1));
    }
}

// ---------------------------------------------------------------- launch
extern "C" void kernel_launch(void* const* d_in, const int* in_sizes, int n_in,
                              void* d_out, int out_size, void* d_ws, size_t ws_size,
                              hipStream_t stream) {
    const float* x     = (const float*)d_in[0];
    const float* W     = (const float*)d_in[1];
    const float* att_s = (const float*)d_in[2];
    const float* att_d = (const float*)d_in[3];
    const float* bias  = (const float*)d_in[4];
    const int*   ei    = (const int*)d_in[5];
    const int*   batch = (const int*)d_in[6];
    float*       out   = (float*)d_out;

    char* ws = (char*)d_ws;
    size_t off = 0;
    auto alloc = [&](size_t bytes) -> void* {
        void* p = ws + off;
        off += (bytes + 255) & ~(size_t)255;
        return p;
    };
    const int NB = (N_NODES + 1023) / 1024;   // 49
    __bf16*   h2       = (__bf16*)alloc((size_t)N_NODES * HID * 2);
    __bf16*   wt       = (__bf16*)alloc((size_t)HID * IN_DIM * 2);
    float*    a_src    = (float*)alloc((size_t)N_NODES * 4);
    float*    a_dst    = (float*)alloc((size_t)N_NODES * 4);
    float*    pself    = (float*)alloc((size_t)N_NODES * 4);
    int*      deg      = (int*)alloc((size_t)N_NODES * 4);
    int*      rowstart = (int*)alloc((size_t)(N_NODES + 1) * 4);
    int*      cursor   = (int*)alloc((size_t)N_NODES * 4);
    int*      bsum     = (int*)alloc((size_t)NB * 4);
    int*      boff     = (int*)alloc((size_t)NB * 4);
    unsigned* csrp     = (unsigned*)alloc((size_t)N_EDGES * 4);
    (void)ws_size; (void)in_sizes; (void)n_in;

    hipLaunchKernelGGL(prep_kernel, dim3(512), dim3(256), 0, stream,
                       W, wt, deg, out, out_size);
    hipLaunchKernelGGL(gemm_kernel, dim3((N_NODES + 63) / 64), dim3(256), 0, stream,
                       x, wt, h2, att_s, att_d, a_src, a_dst, pself);
    hipLaunchKernelGGL(hist_kernel, dim3((N_EDGES + 255) / 256), dim3(256), 0, stream,
                       ei, deg);
    hipLaunchKernelGGL(scan1_kernel, dim3(NB), dim3(256), 0, stream, deg, bsum);
    hipLaunchKernelGGL(scan2_kernel, dim3(1), dim3(64), 0, stream, bsum, boff, rowstart, NB);
    hipLaunchKernelGGL(scan3_kernel, dim3(NB), dim3(256), 0, stream, deg, boff, rowstart, cursor);
    hipLaunchKernelGGL(scatter_kernel, dim3((N_EDGES + 255) / 256), dim3(256), 0, stream,
                       ei, cursor, csrp, a_src, a_dst);
    hipLaunchKernelGGL(aggregate_kernel, dim3(AGG_WAVES / 4), dim3(256), 0, stream,
                       (const unsigned*)h2, pself, rowstart, csrp, bias, batch, out);
}

// Round 4
// 524.011 us; speedup vs baseline: 1.1586x; 1.1129x over previous
//
#include <hip/hip_runtime.h>
#include <hip/hip_bf16.h>

#define N_NODES 50000
#define N_EDGES 1600000
#define IN_DIM 1024
#define HID 128
#define AGG_WAVES 6144          // 1536 blocks x 4 waves = 24 waves/CU at launch_bounds(256,6)

typedef __bf16 bf16x8 __attribute__((ext_vector_type(8)));
typedef float f32x4 __attribute__((ext_vector_type(4)));
typedef __bf16 bf16x4 __attribute__((ext_vector_type(4)));

// bf16-pair (packed in uint) -> 2 floats (features 2l = low, 2l+1 = high)
__device__ __forceinline__ float2 bf2f(unsigned u) {
    return make_float2(__uint_as_float(u << 16), __uint_as_float(u & 0xffff0000u));
}
__device__ __forceinline__ float lrelu(float v) { return v > 0.f ? v : 0.2f * v; }
// fp16 bits (in low 16 of arg) -> float
__device__ __forceinline__ float f16tof(unsigned bits) {
    return (float)__builtin_bit_cast(_Float16, (unsigned short)bits);
}

// ---------------------------------------------------------------- prep: zero deg/out + W^T->bf16
__global__ void prep_kernel(const float* __restrict__ W, __bf16* __restrict__ wt,
                            int* __restrict__ deg, float* __restrict__ out, int out_n) {
    int i = blockIdx.x * 256 + threadIdx.x;       // grid covers 131072
    if (i < N_NODES) deg[i] = 0;
    if (i < out_n) out[i] = 0.0f;
    if (i < HID * IN_DIM) {
        int n = i >> 10, k = i & 1023;
        wt[i] = (__bf16)W[(size_t)k * HID + n];
    }
}

// ---------------------------------------------------------------- GEMM h = x @ W (bf16 MFMA)
// BM=64 x BN=128 (full HID), BK=32, 782 blocks. Double-buffered LDS, one barrier
// per k-iter, register prefetch of next tile. Epilogue emits a_src/a_dst and
// pself = exp(lrelu(a_src+a_dst)).
__global__ __launch_bounds__(256) void gemm_kernel(const float* __restrict__ x,
                                                   const __bf16* __restrict__ wt,
                                                   __bf16* __restrict__ h2,
                                                   const float* __restrict__ att_s,
                                                   const float* __restrict__ att_d,
                                                   float* __restrict__ o_as,
                                                   float* __restrict__ o_ad,
                                                   float* __restrict__ o_ps) {
    __shared__ __bf16 xa[2][64][40];
    __shared__ __bf16 wb[2][128][40];
    const int t = threadIdx.x;
    const int m0 = blockIdx.x * 64;
    const int wid = t >> 6, lane = t & 63;
    const int lm = lane & 15, q8 = (lane >> 4) * 8;
    const int rw0 = wid * 16;

    float4 xs_reg[2];
    uint2  ws_reg[4];

    auto stage_regs = [&](int k0) {
#pragma unroll
        for (int l = 0; l < 2; ++l) {
            int f = t + l * 256;
            int row = f >> 3, kq = f & 7;
            int gr = m0 + row;
            float4 v = make_float4(0.f, 0.f, 0.f, 0.f);
            if (gr < N_NODES)
                v = *(const float4*)(x + (size_t)gr * IN_DIM + k0 + kq * 4);
            xs_reg[l] = v;
        }
#pragma unroll
        for (int l = 0; l < 4; ++l) {
            int f = t + l * 256;
            int n = f >> 3, c = f & 7;
            ws_reg[l] = *(const uint2*)(wt + (size_t)n * IN_DIM + k0 + c * 4);
        }
    };
    auto regs_to_lds = [&](int b) {
#pragma unroll
        for (int l = 0; l < 2; ++l) {
            int f = t + l * 256;
            int row = f >> 3, kq = f & 7;
            bf16x4 v;
            v[0] = (__bf16)xs_reg[l].x; v[1] = (__bf16)xs_reg[l].y;
            v[2] = (__bf16)xs_reg[l].z; v[3] = (__bf16)xs_reg[l].w;
            *(bf16x4*)&xa[b][row][kq * 4] = v;
        }
#pragma unroll
        for (int l = 0; l < 4; ++l) {
            int f = t + l * 256;
            int n = f >> 3, c = f & 7;
            *(uint2*)&wb[b][n][c * 4] = ws_reg[l];
        }
    };

    f32x4 acc[8] = {};
    stage_regs(0);
    regs_to_lds(0);
    __syncthreads();
    for (int it = 0; it < 32; ++it) {
        const int cur = it & 1;
        if (it + 1 < 32) stage_regs((it + 1) * 32);   // global loads in flight during MFMA
        bf16x8 af = *(const bf16x8*)&xa[cur][rw0 + lm][q8];
#pragma unroll
        for (int ct = 0; ct < 8; ++ct) {
            bf16x8 bfr = *(const bf16x8*)&wb[cur][ct * 16 + lm][q8];
            acc[ct] = __builtin_amdgcn_mfma_f32_16x16x32_bf16(af, bfr, acc[ct], 0, 0, 0);
        }
        if (it + 1 < 32) {
            regs_to_lds(cur ^ 1);     // write OTHER buffer: no read-write conflict
            __syncthreads();          // make writes visible for next iter's reads
        }
    }
    // epilogue: C/D layout col=lane&15, row=(lane>>4)*4+reg ; fused att dots
    const int quad = lane >> 4;
    float attsf[8], attdf[8];
#pragma unroll
    for (int ct = 0; ct < 8; ++ct) {
        attsf[ct] = att_s[ct * 16 + lm];
        attdf[ct] = att_d[ct * 16 + lm];
    }
#pragma unroll
    for (int reg = 0; reg < 4; ++reg) {
        int row = m0 + rw0 + quad * 4 + reg;
        float ps = 0.f, pd = 0.f;
#pragma unroll
        for (int ct = 0; ct < 8; ++ct) {
            float v = acc[ct][reg];
            ps = fmaf(v, attsf[ct], ps);
            pd = fmaf(v, attdf[ct], pd);
        }
#pragma unroll
        for (int o = 8; o; o >>= 1) {
            ps += __shfl_xor(ps, o);
            pd += __shfl_xor(pd, o);
        }
        if (row < N_NODES) {
            if (lm == 0) {
                o_as[row] = ps; o_ad[row] = pd;
                o_ps[row] = __expf(lrelu(ps + pd));   // self-loop weight, precomputed
            }
#pragma unroll
            for (int ct = 0; ct < 8; ++ct)
                h2[(size_t)row * HID + ct * 16 + lm] = (__bf16)acc[ct][reg];
        }
    }
}

// ---------------------------------------------------------------- CSR build
__global__ void hist_kernel(const int* __restrict__ ei, int* __restrict__ deg) {
    int e = blockIdx.x * 256 + threadIdx.x;
    if (e < N_EDGES) atomicAdd(&deg[ei[N_EDGES + e]], 1);
}

__global__ void scan1_kernel(const int* __restrict__ deg, int* __restrict__ bsum) {
    int b = blockIdx.x, t = threadIdx.x;
    int base = b * 1024 + t * 4;
    int s = 0;
#pragma unroll
    for (int j = 0; j < 4; ++j) {
        int idx = base + j;
        if (idx < N_NODES) s += deg[idx];
    }
    for (int o = 32; o; o >>= 1) s += __shfl_xor(s, o);
    __shared__ int wsum[4];
    int lane = t & 63, w = t >> 6;
    if (lane == 0) wsum[w] = s;
    __syncthreads();
    if (t == 0) bsum[b] = wsum[0] + wsum[1] + wsum[2] + wsum[3];
}

__global__ void scan2_kernel(const int* __restrict__ bsum, int* __restrict__ boff,
                             int* __restrict__ rowstart, int nb) {
    if (threadIdx.x == 0 && blockIdx.x == 0) {
        int run = 0;
        for (int i = 0; i < nb; ++i) { boff[i] = run; run += bsum[i]; }
        rowstart[N_NODES] = run;
    }
}

// also materializes cursor = rowstart copy for scatter's atomic slot claim
__global__ void scan3_kernel(const int* __restrict__ deg, const int* __restrict__ boff,
                             int* __restrict__ rowstart, int* __restrict__ cursor) {
    int b = blockIdx.x, t = threadIdx.x;
    int base = b * 1024 + t * 4;
    int v[4]; int s = 0;
#pragma unroll
    for (int j = 0; j < 4; ++j) {
        int idx = base + j;
        v[j] = (idx < N_NODES) ? deg[idx] : 0;
        s += v[j];
    }
    int lane = t & 63, w = t >> 6;
    int inc = s;
    for (int o = 1; o < 64; o <<= 1) {
        int u = __shfl_up(inc, o);
        if (lane >= o) inc += u;
    }
    __shared__ int wt[4];
    if (lane == 63) wt[w] = inc;
    __syncthreads();
    int woff = 0;
    for (int i = 0; i < w; ++i) woff += wt[i];
    int run = woff + inc - s + boff[b];
#pragma unroll
    for (int j = 0; j < 4; ++j) {
        int idx = base + j;
        if (idx < N_NODES) {
            rowstart[idx] = run;
            cursor[idx] = run;
            run += v[j];
        }
    }
}

// scatter: slot via atomic cursor. PACKED payload: u16 src | fp16 pe (4B/edge).
// src < 65536 OK (N=50000); pe in [~e^-1, ~e^3], well inside fp16; 2^-11 rel
// error is ~10x below the bf16 noise floor.
__global__ void scatter_kernel(const int* __restrict__ ei, int* __restrict__ cursor,
                               unsigned* __restrict__ csrp, const float* __restrict__ a_src,
                               const float* __restrict__ a_dst) {
    int e = blockIdx.x * 256 + threadIdx.x;
    if (e >= N_EDGES) return;
    int s = ei[e], d = ei[N_EDGES + e];
    int slot = atomicAdd(&cursor[d], 1);
    float pe = __expf(lrelu(a_src[s] + a_dst[d]));
    unsigned short hb = __builtin_bit_cast(unsigned short, (_Float16)pe);
    csrp[slot] = (unsigned)s | ((unsigned)hb << 16);
}

// ---------------------------------------------------------------- aggregate+pool
// R0's measured-best shape at its measured-best register budget: lane owns
// features {2l,2l+1}; 64-edge chunk per lane; 16-deep register batch of
// shfl-broadcast packed (src|pe) -> 16 independent row-gathers in flight.
// launch_bounds(256,6): VGPR cap 85 -- R3's bounds(256,8) capped at 64 and
// SPILLED the 32-reg batch arrays to scratch (the +76us regression). Denominator
// now accumulated redundantly per-lane from the broadcast pe (zero extra DS ops;
// drops the 6-step shfl_xor reduce per chunk).
__global__ __launch_bounds__(256, 6) void aggregate_kernel(
    const unsigned* __restrict__ h2u, const float* __restrict__ pself_a,
    const int* __restrict__ rowstart, const unsigned* __restrict__ csrp,
    const float* __restrict__ bias, const int* __restrict__ batch,
    float* __restrict__ out) {
    const int wid = threadIdx.x >> 6, lane = threadIdx.x & 63;
    const int w = blockIdx.x * 4 + wid;
    const int q = N_NODES / AGG_WAVES;
    const int r = N_NODES - q * AGG_WAVES;
    int n0 = w * q + (w < r ? w : r);
    int n1 = n0 + q + (w < r ? 1 : 0);
    const float b0 = bias[2 * lane], b1 = bias[2 * lane + 1];

    int gcur = -1;
    float m0 = 0.f, m1 = 0.f;
    for (int n = n0; n < n1; ++n) {
        int rs = rowstart[n], re = rowstart[n + 1];
        float psf = pself_a[n];
        float2 hv = bf2f(h2u[((unsigned)n << 6) | (unsigned)lane]);
        float denom = psf;
        float2 acc = make_float2(psf * hv.x, psf * hv.y);
        for (int base = rs; base < re; base += 64) {
            int cnt = re - base; if (cnt > 64) cnt = 64;
            unsigned sp = 0u;                 // src=0, pe=0 for invalid lanes
            if (base + lane < re) sp = csrp[base + lane];
            for (int e = 0; e < cnt; e += 16) {
                unsigned bb[16], uu[16];
#pragma unroll
                for (int i = 0; i < 16; ++i) {
                    bb[i] = (unsigned)__shfl((int)sp, e + i);
                    uu[i] = h2u[((bb[i] & 0xffffu) << 6) | (unsigned)lane];
                }
#pragma unroll
                for (int i = 0; i < 16; ++i) {
                    float2 g = bf2f(uu[i]);
                    float p = f16tof(bb[i] >> 16);
                    acc.x = fmaf(p, g.x, acc.x);
                    acc.y = fmaf(p, g.y, acc.y);
                    denom += p;               // every lane sums every pe: no shfl reduce
                }
            }
        }
        float inv = 1.0f / denom;
        float o0 = fmaxf(fmaf(acc.x, inv, b0), 0.0f);
        float o1 = fmaxf(fmaf(acc.y, inv, b1), 0.0f);
        int g = batch[n];
        if (g != gcur) {
            if (gcur >= 0) {
                unsigned* outp = (unsigned*)(out + (size_t)gcur * HID);
                atomicMax(&outp[2 * lane], __float_as_uint(m0));
                atomicMax(&outp[2 * lane + 1], __float_as_uint(m1));
            }
            gcur = g; m0 = o0; m1 = o1;
        } else {
            m0 = fmaxf(m0, o0); m1 = fmaxf(m1, o1);
        }
    }
    if (gcur >= 0) {
        unsigned* outp = (unsigned*)(out + (size_t)gcur * HID);
        atomicMax(&outp[2 * lane], __float_as_uint(m0));
        atomicMax(&outp[2 * lane + 1], __float_as_uint(m1));
    }
}

// ---------------------------------------------------------------- launch
extern "C" void kernel_launch(void* const* d_in, const int* in_sizes, int n_in,
                              void* d_out, int out_size, void* d_ws, size_t ws_size,
                              hipStream_t stream) {
    const float* x     = (const float*)d_in[0];
    const float* W     = (const float*)d_in[1];
    const float* att_s = (const float*)d_in[2];
    const float* att_d = (const float*)d_in[3];
    const float* bias  = (const float*)d_in[4];
    const int*   ei    = (const int*)d_in[5];
    const int*   batch = (const int*)d_in[6];
    float*       out   = (float*)d_out;

    char* ws = (char*)d_ws;
    size_t off = 0;
    auto alloc = [&](size_t bytes) -> void* {
        void* p = ws + off;
        off += (bytes + 255) & ~(size_t)255;
        return p;
    };
    const int NB = (N_NODES + 1023) / 1024;   // 49
    __bf16*   h2       = (__bf16*)alloc((size_t)N_NODES * HID * 2);
    __bf16*   wt       = (__bf16*)alloc((size_t)HID * IN_DIM * 2);
    float*    a_src    = (float*)alloc((size_t)N_NODES * 4);
    float*    a_dst    = (float*)alloc((size_t)N_NODES * 4);
    float*    pself    = (float*)alloc((size_t)N_NODES * 4);
    int*      deg      = (int*)alloc((size_t)N_NODES * 4);
    int*      rowstart = (int*)alloc((size_t)(N_NODES + 1) * 4);
    int*      cursor   = (int*)alloc((size_t)N_NODES * 4);
    int*      bsum     = (int*)alloc((size_t)NB * 4);
    int*      boff     = (int*)alloc((size_t)NB * 4);
    unsigned* csrp     = (unsigned*)alloc((size_t)N_EDGES * 4);
    (void)ws_size; (void)in_sizes; (void)n_in;

    hipLaunchKernelGGL(prep_kernel, dim3(512), dim3(256), 0, stream,
                       W, wt, deg, out, out_size);
    hipLaunchKernelGGL(gemm_kernel, dim3((N_NODES + 63) / 64), dim3(256), 0, stream,
                       x, wt, h2, att_s, att_d, a_src, a_dst, pself);
    hipLaunchKernelGGL(hist_kernel, dim3((N_EDGES + 255) / 256), dim3(256), 0, stream,
                       ei, deg);
    hipLaunchKernelGGL(scan1_kernel, dim3(NB), dim3(256), 0, stream, deg, bsum);
    hipLaunchKernelGGL(scan2_kernel, dim3(1), dim3(64), 0, stream, bsum, boff, rowstart, NB);
    hipLaunchKernelGGL(scan3_kernel, dim3(NB), dim3(256), 0, stream, deg, boff, rowstart, cursor);
    hipLaunchKernelGGL(scatter_kernel, dim3((N_EDGES + 255) / 256), dim3(256), 0, stream,
                       ei, cursor, csrp, a_src, a_dst);
    hipLaunchKernelGGL(aggregate_kernel, dim3(AGG_WAVES / 4), dim3(256), 0, stream,
                       (const unsigned*)h2, pself, rowstart, csrp, bias, batch, out);
}